// Round 4
// baseline (103.971 us; speedup 1.0000x reference)
//
#include <hip/hip_runtime.h>

// WaveKANLinear: out[n,o] = sum_d mexhat((ln(x)[n,d]-t[o,d])/s[o,d]) * ww[o,d]
//                           + silu(sum_d x[n,d]*bw[o,d])
// N=8192, D=128, O=128, float32. VALU/latency-bound: 134M exp evals.
// clip(+-10) dead: |mexhat| <= 0.8673.
//
// R4: BLOCK=1024 (8 waves/SIMD, 2048 thr/CU cap), thread = o x 2 rows,
//     explicit wsW prefetch (1 d-iter ahead, modular index, branch-free).
//     u = (x*is - t*is), e = exp2(-u^2), term = (u^2 - C1)*e*(ww*MEX_C/C1).

#define D_DIM 128
#define O_DIM 128
#define ROWS  16     // rows per block
#define BLOCK 1024   // 16 waves: o = tid&127, group g = tid>>7 (2 rows each)

#define C1     0.72134752f   // 0.5*log2(e); exp(-z^2/2) = exp2(-C1*z^2)
#define SQRT_C 0.84932180f   // sqrt(C1)
#define WWK    1.2023651f    // MEX_C / C1, MEX_C = 2/(sqrt(3)*pi^0.25)
#define LOG2E  1.44269504f

// Prep: transpose weights to [d][o] float4 {t*is2, is2, ww*WWK, bw},
// is2 = SQRT_C / (softplus(scale)+0.1)
__global__ __launch_bounds__(256) void wavekan_prep(
    const float* __restrict__ scale,
    const float* __restrict__ trans,
    const float* __restrict__ ww,
    const float* __restrict__ bw,
    float4* __restrict__ wsW)
{
    int idx = blockIdx.x * blockDim.x + threadIdx.x;   // = o*128 + d
    if (idx >= O_DIM * D_DIM) return;
    int o = idx >> 7;
    int d = idx & (D_DIM - 1);
    float sc = scale[idx];
    float sp = fmaxf(sc, 0.0f) + log1pf(__expf(-fabsf(sc)));  // stable softplus
    float is2 = SQRT_C / (sp + 0.1f);
    float4 w;
    w.x = trans[idx] * is2;
    w.y = is2;
    w.z = ww[idx] * WWK;
    w.w = bw[idx];
    wsW[d * O_DIM + o] = w;
}

template<bool USE_WS>
__global__ __launch_bounds__(BLOCK, 8) void wavekan_main(
    const float* __restrict__ x,
    const float* __restrict__ scale,
    const float* __restrict__ trans,
    const float* __restrict__ ww,
    const float* __restrict__ bw,
    const float* __restrict__ gamma,
    const float* __restrict__ beta,
    const float4* __restrict__ wsW,
    float* __restrict__ out,
    int N)
{
    __shared__ float2 s_lr[ROWS * D_DIM];   // {layernormed, raw} interleaved

    const int tid  = threadIdx.x;
    const int row0 = blockIdx.x * ROWS;

    // ---- Phase 1: 1024 threads, one wave per row (64 lanes x 2 elems) ----
    {
        const int r  = tid >> 6;        // local row 0..15 == wave id
        const int j  = tid & 63;        // lane
        const int d0 = j * 2;           // 2 elems per lane
        const int grow = row0 + r;

        float2 v2 = make_float2(0.f, 0.f);
        if (grow < N)
            v2 = *reinterpret_cast<const float2*>(x + (size_t)grow * D_DIM + d0);

        float sum = v2.x + v2.y;
        float ssq = v2.x * v2.x + v2.y * v2.y;
        #pragma unroll
        for (int m = 1; m < 64; m <<= 1) {   // full-wave butterfly
            sum += __shfl_xor(sum, m, 64);
            ssq += __shfl_xor(ssq, m, 64);
        }
        const float mean = sum * (1.0f / D_DIM);
        const float var  = ssq * (1.0f / D_DIM) - mean * mean;
        const float rstd = rsqrtf(var + 1e-5f);

        float2 g2 = *reinterpret_cast<const float2*>(gamma + d0);
        float2 b2 = *reinterpret_cast<const float2*>(beta + d0);

        s_lr[r * D_DIM + d0]     = make_float2((v2.x - mean) * rstd * g2.x + b2.x, v2.x);
        s_lr[r * D_DIM + d0 + 1] = make_float2((v2.y - mean) * rstd * g2.y + b2.y, v2.y);
    }
    __syncthreads();

    // ---- Phase 2: thread = output column o x 2 rows, prefetched weights ----
    const int o = tid & (O_DIM - 1);
    const int g = tid >> 7;  // row-group 0..7
    const float2* __restrict__ lr = s_lr + g * 2 * D_DIM;

    float accw0 = 0.f, accw1 = 0.f, accb0 = 0.f, accb1 = 0.f;

    if (USE_WS) {
        float4 w = wsW[o];               // d = 0
        #pragma unroll 4
        for (int d = 0; d < D_DIM; ++d) {
            // prefetch next iteration's weights (wraps to d=0 at the end; free)
            float4 wn = wsW[(((d + 1) & (D_DIM - 1)) << 7) + o];
            float2 v0 = lr[d];           // row 2g   (ds_read_b64 broadcast)
            float2 v1 = lr[D_DIM + d];   // row 2g+1

            float u0 = fmaf(v0.x, w.y, -w.x);
            float u1 = fmaf(v1.x, w.y, -w.x);
            float q0 = u0 * u0;
            float q1 = u1 * u1;
            float e0 = __builtin_amdgcn_exp2f(-q0);
            float e1 = __builtin_amdgcn_exp2f(-q1);
            accw0 = fmaf((q0 - C1) * e0, w.z, accw0);
            accw1 = fmaf((q1 - C1) * e1, w.z, accw1);
            accb0 = fmaf(v0.y, w.w, accb0);
            accb1 = fmaf(v1.y, w.w, accb1);
            w = wn;
        }
    } else {
        // fallback: direct reads + on-the-fly softplus (uncoalesced, slow)
        for (int d = 0; d < D_DIM; ++d) {
            int idx = o * D_DIM + d;
            float sc = scale[idx];
            float sp = fmaxf(sc, 0.0f) + log1pf(__expf(-fabsf(sc)));
            float is  = SQRT_C / (sp + 0.1f);
            float tws = trans[idx] * is;
            float wwk = ww[idx] * WWK;
            float bwv = bw[idx];
            float2 v0 = lr[d];
            float2 v1 = lr[D_DIM + d];
            float u0 = fmaf(v0.x, is, -tws);
            float u1 = fmaf(v1.x, is, -tws);
            float q0 = u0 * u0;
            float q1 = u1 * u1;
            accw0 = fmaf((q0 - C1) * __builtin_amdgcn_exp2f(-q0), wwk, accw0);
            accw1 = fmaf((q1 - C1) * __builtin_amdgcn_exp2f(-q1), wwk, accw1);
            accb0 = fmaf(v0.y, bwv, accb0);
            accb1 = fmaf(v1.y, bwv, accb1);
        }
    }

    // ---- Epilogue: out = wavelet + silu(base) ----
    {
        const int rr0 = row0 + g * 2;
        if (rr0 < N) {
            float sig0 = 1.0f / (1.0f + __builtin_amdgcn_exp2f(-LOG2E * accb0));
            out[(size_t)rr0 * O_DIM + o] = accw0 + accb0 * sig0;
        }
        if (rr0 + 1 < N) {
            float sig1 = 1.0f / (1.0f + __builtin_amdgcn_exp2f(-LOG2E * accb1));
            out[(size_t)(rr0 + 1) * O_DIM + o] = accw1 + accb1 * sig1;
        }
    }
}

extern "C" void kernel_launch(void* const* d_in, const int* in_sizes, int n_in,
                              void* d_out, int out_size, void* d_ws, size_t ws_size,
                              hipStream_t stream) {
    const float* x     = (const float*)d_in[0];
    const float* scale = (const float*)d_in[1];
    const float* trans = (const float*)d_in[2];
    const float* ww    = (const float*)d_in[3];
    const float* bw    = (const float*)d_in[4];
    const float* gamma = (const float*)d_in[5];
    const float* beta  = (const float*)d_in[6];
    float* out = (float*)d_out;

    const int N = in_sizes[0] / D_DIM;       // 8192
    const int grid = (N + ROWS - 1) / ROWS;  // 512

    const size_t ws_needed = (size_t)O_DIM * D_DIM * sizeof(float4);  // 256 KB
    if (ws_size >= ws_needed) {
        wavekan_prep<<<(O_DIM * D_DIM + 255) / 256, 256, 0, stream>>>(
            scale, trans, ww, bw, (float4*)d_ws);
        wavekan_main<true><<<grid, BLOCK, 0, stream>>>(
            x, scale, trans, ww, bw, gamma, beta, (const float4*)d_ws, out, N);
    } else {
        wavekan_main<false><<<grid, BLOCK, 0, stream>>>(
            x, scale, trans, ww, bw, gamma, beta, nullptr, out, N);
    }
}

// Round 5
// 98.270 us; speedup vs baseline: 1.0580x; 1.0580x over previous
//
#include <hip/hip_runtime.h>

// WaveKANLinear: out[n,o] = sum_d mexhat((ln(x)[n,d]-t[o,d])/s[o,d]) * ww[o,d]
//                           + silu(sum_d x[n,d]*bw[o,d])
// N=8192, D=128, O=128, float32.
// R5: weights staged through LDS in d-chunks of 16 (breaks the per-wave 1 GB
//     L1 re-read that capped R4 at 42us), register prefetch of next chunk,
//     x repacked [d][pair]{ln0,ln1,raw0,raw1} for b128 broadcast + packed-f32.

#define D_DIM 128
#define O_DIM 128
#define ROWS  16     // rows per block
#define BLOCK 1024   // 16 waves: o = tid&127, pair g = tid>>7 (2 rows each)
#define CHUNK 16     // d-rows staged per LDS chunk
#define NCHUNK (D_DIM / CHUNK)
#define XSTRIDE 9    // float4 stride for s_x rows (pad: phase-1 write conflicts)

#define C1     0.72134752f   // 0.5*log2(e); exp(-z^2/2) = exp2(-C1*z^2)
#define SQRT_C 0.84932180f   // sqrt(C1)
#define WWK    1.2023651f    // MEX_C / C1, MEX_C = 2/(sqrt(3)*pi^0.25)
#define LOG2E  1.44269504f

typedef float v2f __attribute__((ext_vector_type(2)));

// Prep: transpose weights to [d][o] float4 {t*is2, is2, ww*WWK, bw},
// is2 = SQRT_C / (softplus(scale)+0.1)
__global__ __launch_bounds__(256) void wavekan_prep(
    const float* __restrict__ scale,
    const float* __restrict__ trans,
    const float* __restrict__ ww,
    const float* __restrict__ bw,
    float4* __restrict__ wsW)
{
    int idx = blockIdx.x * blockDim.x + threadIdx.x;   // = o*128 + d
    if (idx >= O_DIM * D_DIM) return;
    int o = idx >> 7;
    int d = idx & (D_DIM - 1);
    float sc = scale[idx];
    float sp = fmaxf(sc, 0.0f) + log1pf(__expf(-fabsf(sc)));  // stable softplus
    float is2 = SQRT_C / (sp + 0.1f);
    float4 w;
    w.x = trans[idx] * is2;
    w.y = is2;
    w.z = ww[idx] * WWK;
    w.w = bw[idx];
    wsW[d * O_DIM + o] = w;
}

template<bool USE_WS>
__global__ __launch_bounds__(BLOCK, 8) void wavekan_main(
    const float* __restrict__ x,
    const float* __restrict__ scale,
    const float* __restrict__ trans,
    const float* __restrict__ ww,
    const float* __restrict__ bw,
    const float* __restrict__ gamma,
    const float* __restrict__ beta,
    const float4* __restrict__ wsW,
    float* __restrict__ out,
    int N)
{
    // s_x[d * XSTRIDE + pair] = {ln_row0, ln_row1, raw_row0, raw_row1}
    __shared__ float4 s_x[D_DIM * XSTRIDE];          // 18 KB
    __shared__ float4 s_w[CHUNK * O_DIM];            // 32 KB

    const int tid  = threadIdx.x;
    const int row0 = blockIdx.x * ROWS;

    // ---- Phase 1: one wave per row (64 lanes x 2 elems), LayerNorm -> LDS ----
    {
        const int r  = tid >> 6;        // local row 0..15 == wave id
        const int j  = tid & 63;        // lane
        const int d0 = j * 2;           // 2 elems per lane
        const int grow = row0 + r;

        float2 v2 = make_float2(0.f, 0.f);
        if (grow < N)
            v2 = *reinterpret_cast<const float2*>(x + (size_t)grow * D_DIM + d0);

        float sum = v2.x + v2.y;
        float ssq = v2.x * v2.x + v2.y * v2.y;
        #pragma unroll
        for (int m = 1; m < 64; m <<= 1) {   // full-wave butterfly
            sum += __shfl_xor(sum, m, 64);
            ssq += __shfl_xor(ssq, m, 64);
        }
        const float mean = sum * (1.0f / D_DIM);
        const float var  = ssq * (1.0f / D_DIM) - mean * mean;
        const float rstd = rsqrtf(var + 1e-5f);

        float2 g2 = *reinterpret_cast<const float2*>(gamma + d0);
        float2 b2 = *reinterpret_cast<const float2*>(beta + d0);

        const int p  = r >> 1;          // pair index 0..7
        const int h  = r & 1;           // which row of the pair
        float* c0 = reinterpret_cast<float*>(&s_x[d0 * XSTRIDE + p]);
        float* c1 = reinterpret_cast<float*>(&s_x[(d0 + 1) * XSTRIDE + p]);
        c0[h]     = (v2.x - mean) * rstd * g2.x + b2.x;   // ln
        c0[2 + h] = v2.x;                                  // raw
        c1[h]     = (v2.y - mean) * rstd * g2.y + b2.y;
        c1[2 + h] = v2.y;
    }

    // ---- Phase 2: thread = column o x 2 rows; weights via LDS chunks ----
    const int o = tid & (O_DIM - 1);
    const int g = tid >> 7;  // pair 0..7

    v2f accw = {0.f, 0.f};
    v2f accb = {0.f, 0.f};

    if (USE_WS) {
        float4 r0 = wsW[tid];             // prefetch chunk 0
        float4 r1 = wsW[tid + BLOCK];
        for (int c = 0; c < NCHUNK; ++c) {
            __syncthreads();              // prev chunk compute done (+phase-1 at c=0)
            s_w[tid]         = r0;
            s_w[tid + BLOCK] = r1;
            if (c + 1 < NCHUNK) {         // prefetch next chunk during compute
                r0 = wsW[(c + 1) * (CHUNK * O_DIM) + tid];
                r1 = wsW[(c + 1) * (CHUNK * O_DIM) + tid + BLOCK];
            }
            __syncthreads();              // staging visible

            #pragma unroll
            for (int dl = 0; dl < CHUNK; ++dl) {
                float4 w  = s_w[dl * O_DIM + o];                 // per-lane b128, conflict-free
                float4 xx = s_x[(c * CHUNK + dl) * XSTRIDE + g]; // broadcast b128
                v2f xln = {xx.x, xx.y};
                v2f xrw = {xx.z, xx.w};
                v2f u   = xln * w.y - w.x;       // pk_fma
                v2f q   = u * u;
                v2f s1  = q - C1;
                v2f e   = {__builtin_amdgcn_exp2f(-q.x),
                           __builtin_amdgcn_exp2f(-q.y)};
                accw += (s1 * e) * w.z;
                accb += xrw * w.w;
            }
        }
    } else {
        __syncthreads();
        // fallback: direct global reads + on-the-fly softplus (slow, correct)
        for (int d = 0; d < D_DIM; ++d) {
            int idx = o * D_DIM + d;
            float sc = scale[idx];
            float sp = fmaxf(sc, 0.0f) + log1pf(__expf(-fabsf(sc)));
            float is  = SQRT_C / (sp + 0.1f);
            float tws = trans[idx] * is;
            float wwk = ww[idx] * WWK;
            float bwv = bw[idx];
            float4 xx = s_x[d * XSTRIDE + g];
            v2f xln = {xx.x, xx.y};
            v2f xrw = {xx.z, xx.w};
            v2f u   = xln * is - tws;
            v2f q   = u * u;
            v2f s1  = q - C1;
            v2f e   = {__builtin_amdgcn_exp2f(-q.x),
                       __builtin_amdgcn_exp2f(-q.y)};
            accw += (s1 * e) * wwk;
            accb += xrw * bwv;
        }
    }

    // ---- Epilogue: out = wavelet + silu(base) ----
    {
        const int rr0 = row0 + g * 2;
        if (rr0 < N) {
            float sig0 = 1.0f / (1.0f + __builtin_amdgcn_exp2f(-LOG2E * accb.x));
            out[(size_t)rr0 * O_DIM + o] = accw.x + accb.x * sig0;
        }
        if (rr0 + 1 < N) {
            float sig1 = 1.0f / (1.0f + __builtin_amdgcn_exp2f(-LOG2E * accb.y));
            out[(size_t)(rr0 + 1) * O_DIM + o] = accw.y + accb.y * sig1;
        }
    }
}

extern "C" void kernel_launch(void* const* d_in, const int* in_sizes, int n_in,
                              void* d_out, int out_size, void* d_ws, size_t ws_size,
                              hipStream_t stream) {
    const float* x     = (const float*)d_in[0];
    const float* scale = (const float*)d_in[1];
    const float* trans = (const float*)d_in[2];
    const float* ww    = (const float*)d_in[3];
    const float* bw    = (const float*)d_in[4];
    const float* gamma = (const float*)d_in[5];
    const float* beta  = (const float*)d_in[6];
    float* out = (float*)d_out;

    const int N = in_sizes[0] / D_DIM;       // 8192
    const int grid = (N + ROWS - 1) / ROWS;  // 512

    const size_t ws_needed = (size_t)O_DIM * D_DIM * sizeof(float4);  // 256 KB
    if (ws_size >= ws_needed) {
        wavekan_prep<<<(O_DIM * D_DIM + 255) / 256, 256, 0, stream>>>(
            scale, trans, ww, bw, (float4*)d_ws);
        wavekan_main<true><<<grid, BLOCK, 0, stream>>>(
            x, scale, trans, ww, bw, gamma, beta, (const float4*)d_ws, out, N);
    } else {
        wavekan_main<false><<<grid, BLOCK, 0, stream>>>(
            x, scale, trans, ww, bw, gamma, beta, nullptr, out, N);
    }
}